// Round 4
// baseline (101.711 us; speedup 1.0000x reference)
//
#include <hip/hip_runtime.h>
#include <math.h>

#define LOG2E 1.4426950408889634f

typedef short  short8 __attribute__((ext_vector_type(8)));
typedef float  f32x4  __attribute__((ext_vector_type(4)));
typedef unsigned short ushort8 __attribute__((ext_vector_type(8)));

__device__ inline unsigned short f2bf(float f) {   // f32 -> bf16 bits, RNE
    unsigned int u = __float_as_uint(f);
    return (unsigned short)((u + 0x7FFFu + ((u >> 16) & 1u)) >> 16);
}

__device__ inline float row_norm16(const float4 v0, const float4 v1,
                                   const float4 v2, const float4 v3) {
    return v0.x*v0.x + v0.y*v0.y + v0.z*v0.z + v0.w*v0.w
         + v1.x*v1.x + v1.y*v1.y + v1.z*v1.z + v1.w*v1.w
         + v2.x*v2.x + v2.y*v2.y + v2.z*v2.z + v2.w*v2.w
         + v3.x*v3.x + v3.y*v3.y + v3.z*v3.z + v3.w*v3.w;
}

// One-time: train -> bf16, 0.5*log2e*norms for train/test, zero counters.
__global__ __launch_bounds__(256) void kde_prep(
    const float* __restrict__ trainX, const float* __restrict__ testX,
    unsigned short* __restrict__ trainH, float* __restrict__ trainN,
    float* __restrict__ testN, int* __restrict__ counters,
    int nTrain, int nTest, int nCnt)
{
    int j = blockIdx.x * 256 + threadIdx.x;
    if (j < nCnt) counters[j] = 0;
    if (j < nTrain) {
        const float4* p = (const float4*)trainX + (size_t)j * 4;
        float4 v0 = p[0], v1 = p[1], v2 = p[2], v3 = p[3];
        trainN[j] = 0.5f * LOG2E * row_norm16(v0, v1, v2, v3);
        ushort8 h0, h1;
        h0[0]=f2bf(v0.x); h0[1]=f2bf(v0.y); h0[2]=f2bf(v0.z); h0[3]=f2bf(v0.w);
        h0[4]=f2bf(v1.x); h0[5]=f2bf(v1.y); h0[6]=f2bf(v1.z); h0[7]=f2bf(v1.w);
        h1[0]=f2bf(v2.x); h1[1]=f2bf(v2.y); h1[2]=f2bf(v2.z); h1[3]=f2bf(v2.w);
        h1[4]=f2bf(v3.x); h1[5]=f2bf(v3.y); h1[6]=f2bf(v3.z); h1[7]=f2bf(v3.w);
        ((ushort8*)trainH)[(size_t)j*2+0] = h0;
        ((ushort8*)trainH)[(size_t)j*2+1] = h1;
    }
    if (j < nTest) {
        const float4* p = (const float4*)testX + (size_t)j * 4;
        testN[j] = 0.5f * LOG2E * row_norm16(p[0], p[1], p[2], p[3]);
    }
}

// Block = 4 waves; wave owns 32 test rows (2 A-frags); blockIdx.y = train split.
// After writing partials, the LAST block of each row-group (device-scope
// counter) reduces the S partials in fixed order and writes out (no 3rd kernel).
__global__ __launch_bounds__(256) void kde_main(
    const float* __restrict__ testX, const unsigned short* __restrict__ trainH,
    const float* __restrict__ trainN, const float* __restrict__ testN,
    float* __restrict__ partials, int* __restrict__ counters,
    float* __restrict__ out, int nTest, int nTrain, int chunk, int S, float Z)
{
    const int lane = threadIdx.x & 63;
    const int w    = threadIdx.x >> 6;
    const int g    = lane >> 4;
    const int l4   = lane & 15;
    const int rowBlockBase = blockIdx.x * 128;
    const int m0   = rowBlockBase + w * 32;

    // Two A fragments (rows m0+f*16+l4), hi/lo bf16 split across K.
    short8 afrag[2];
    #pragma unroll
    for (int f = 0; f < 2; ++f) {
        int m = min(m0 + f * 16 + l4, nTest - 1);
        const float* tp = testX + (size_t)m * 16 + (g & 1) * 8;
        float4 u0 = *(const float4*)tp;
        float4 u1 = *(const float4*)(tp + 4);
        float xv[8] = {u0.x,u0.y,u0.z,u0.w,u1.x,u1.y,u1.z,u1.w};
        #pragma unroll
        for (int i = 0; i < 8; ++i) {
            float fx = xv[i] * LOG2E;
            unsigned short hb = f2bf(fx);
            float hf = __uint_as_float((unsigned int)hb << 16);
            unsigned short lb = f2bf(fx - hf);
            afrag[f][i] = (short)((g < 2) ? hb : lb);
        }
    }

    // Negated test biases for this lane's C rows.
    float nx[2][4];
    #pragma unroll
    for (int f = 0; f < 2; ++f)
        #pragma unroll
        for (int r = 0; r < 4; ++r)
            nx[f][r] = -testN[min(m0 + f*16 + g*4 + r, nTest - 1)];

    const int nBase  = blockIdx.y * chunk;
    const int nTiles = chunk >> 4;

    float rs[2][4] = {{0,0,0,0},{0,0,0,0}};
    for (int t = 0; t < nTiles; ++t) {
        const int n  = nBase + t * 16 + l4;
        const bool vn = n < nTrain;
        const int nc = vn ? n : 0;
        short8 b = *(const short8*)(trainH + (size_t)nc * 16 + (g & 1) * 8);
        const float yn = vn ? trainN[nc] : 1e30f;
        #pragma unroll
        for (int f = 0; f < 2; ++f) {
            f32x4 c;
            c[0] = nx[f][0] - yn; c[1] = nx[f][1] - yn;
            c[2] = nx[f][2] - yn; c[3] = nx[f][3] - yn;
            c = __builtin_amdgcn_mfma_f32_16x16x32_bf16(afrag[f], b, c, 0, 0, 0);
            rs[f][0] += __builtin_amdgcn_exp2f(c[0]);
            rs[f][1] += __builtin_amdgcn_exp2f(c[1]);
            rs[f][2] += __builtin_amdgcn_exp2f(c[2]);
            rs[f][3] += __builtin_amdgcn_exp2f(c[3]);
        }
    }

    // Reduce across the 16 columns (low-4 lane bits).
    #pragma unroll
    for (int off = 1; off <= 8; off <<= 1)
        #pragma unroll
        for (int f = 0; f < 2; ++f)
            #pragma unroll
            for (int r = 0; r < 4; ++r)
                rs[f][r] += __shfl_xor(rs[f][r], off);

    if (l4 == 0) {
        #pragma unroll
        for (int f = 0; f < 2; ++f)
            #pragma unroll
            for (int r = 0; r < 4; ++r) {
                int row = m0 + f*16 + g*4 + r;
                if (row < nTest)
                    partials[(size_t)blockIdx.y * nTest + row] = rs[f][r];
            }
    }

    // Decoupled last-block reduction for this row-group.
    __threadfence();                       // agent release: flush partials
    __syncthreads();
    __shared__ int isLast;
    if (threadIdx.x == 0) {
        int old = atomicAdd(&counters[blockIdx.x], 1);
        isLast = (old == S - 1);
    }
    __syncthreads();
    if (isLast) {
        __builtin_amdgcn_fence(__ATOMIC_ACQUIRE, "agent");  // invalidate stale L1/L2
        int row = rowBlockBase + threadIdx.x;
        if (threadIdx.x < 128 && row < nTest) {
            float s = 0.0f;
            for (int k = 0; k < S; ++k)
                s += partials[(size_t)k * nTest + row];
            out[row] = __logf(s) - Z;
        }
    }
}

extern "C" void kernel_launch(void* const* d_in, const int* in_sizes, int n_in,
                              void* d_out, int out_size, void* d_ws, size_t ws_size,
                              hipStream_t stream) {
    const float* testX  = (const float*)d_in[0];
    const float* trainX = (const float*)d_in[1];
    float* out = (float*)d_out;

    const int D = 16;
    const int nTest  = in_sizes[0] / D;   // 4096
    const int nTrain = in_sizes[1] / D;   // 8192

    const float Z = 0.5f * (float)D * logf(2.0f * (float)M_PI) + logf((float)nTrain);

    const int gx = (nTest + 127) / 128;   // row-groups of 128

    // Choose train split S (power of 2) so everything fits in ws.
    int S = 32;
    size_t offH, offTN, offXN, offC;
    for (;;) {
        offH  = ((size_t)S * nTest * 4 + 63) & ~(size_t)63;
        offTN = offH  + (size_t)nTrain * 32;
        offXN = offTN + (size_t)nTrain * 4;
        offC  = offXN + (size_t)nTest * 4;
        if (offC + (size_t)gx * 4 <= ws_size || S == 1) break;
        S >>= 1;
    }
    float* partials        = (float*)d_ws;
    unsigned short* trainH = (unsigned short*)((char*)d_ws + offH);
    float* trainN          = (float*)((char*)d_ws + offTN);
    float* testN           = (float*)((char*)d_ws + offXN);
    int*   counters        = (int*)((char*)d_ws + offC);

    const int chunk = (((nTrain + S - 1) / S) + 15) & ~15;

    int prepN = max(max(nTrain, nTest), gx);
    kde_prep<<<(prepN + 255) / 256, 256, 0, stream>>>(
        trainX, testX, trainH, trainN, testN, counters, nTrain, nTest, gx);

    dim3 grid(gx, S);
    kde_main<<<grid, 256, 0, stream>>>(
        testX, trainH, trainN, testN, partials, counters, out,
        nTest, nTrain, chunk, S, Z);
}

// Round 5
// 35.989 us; speedup vs baseline: 2.8262x; 2.8262x over previous
//
#include <hip/hip_runtime.h>
#include <math.h>

#define LOG2E 1.4426950408889634f

typedef short short8 __attribute__((ext_vector_type(8)));
typedef float f32x4  __attribute__((ext_vector_type(4)));

__device__ inline unsigned short f2bf(float f) {   // f32 -> bf16 bits, RNE
    unsigned int u = __float_as_uint(f);
    return (unsigned short)((u + 0x7FFFu + ((u >> 16) & 1u)) >> 16);
}

// ONE dispatch. Block = 8 waves, owns 16 test rows; waves partition train.
// Per 16-train tile: inline f32 load + norm + bf16-hi convert, one
// mfma_f32_16x16x32_bf16 (A = [x_hi | x_lo], B = [y_hi | y_hi]) with
// C-init = -(0.5*log2e*(|x|^2+|y|^2)), then exp2 + per-row accumulate.
// Cross-wave: 512B LDS reduce. No atomics, no fences, no workspace.
__global__ __launch_bounds__(512) void kde_fused(
    const float* __restrict__ testX, const float* __restrict__ trainX,
    float* __restrict__ out, int nTest, int nTrain, float Z)
{
    const int tid  = threadIdx.x;
    const int lane = tid & 63;
    const int w    = tid >> 6;            // wave 0..7
    const int NW   = blockDim.x >> 6;     // 8
    const int g    = lane >> 4;
    const int l4   = lane & 15;
    const int h    = g & 1;               // which 8-dim half this lane holds
    const int rowBase = blockIdx.x * 16;

    __shared__ float red[8][16];

    // ---- A fragment (identical in all waves): rows rowBase..rowBase+15 ----
    const int m = min(rowBase + l4, nTest - 1);
    const float4* xp = (const float4*)(testX + (size_t)m * 16);
    float4 x0 = xp[0], x1 = xp[1], x2 = xp[2], x3 = xp[3];
    float xs[16] = {x0.x,x0.y,x0.z,x0.w, x1.x,x1.y,x1.z,x1.w,
                    x2.x,x2.y,x2.z,x2.w, x3.x,x3.y,x3.z,x3.w};
    #pragma unroll
    for (int i = 0; i < 16; ++i) xs[i] *= LOG2E;
    float xn = 0.0f;
    #pragma unroll
    for (int i = 0; i < 16; ++i) xn = fmaf(xs[i], xs[i], xn);
    xn *= 0.5f / LOG2E;                   // 0.5*log2e*||x||^2 of row rowBase+l4

    short8 afrag;
    #pragma unroll
    for (int i = 0; i < 8; ++i) {
        float fx = xs[h * 8 + i];
        unsigned short hb = f2bf(fx);
        float hf = __uint_as_float((unsigned int)hb << 16);
        unsigned short lb = f2bf(fx - hf);
        afrag[i] = (short)((g < 2) ? hb : lb);   // k<16: hi, k>=16: lo
    }

    // nx[r] = -(0.5*log2e*||x||^2) for this lane's C rows (g*4+r), via shuffle.
    float nx[4];
    #pragma unroll
    for (int r = 0; r < 4; ++r)
        nx[r] = -__shfl(xn, (lane & 48) + g * 4 + r);

    // ---- this wave's train slice ----
    const int per   = ((nTrain + NW * 16 - 1) / (NW * 16)) * 16;
    const int tbase = w * per;
    const int nt    = per >> 4;

    float rs0 = 0.f, rs1 = 0.f, rs2 = 0.f, rs3 = 0.f;
    #pragma unroll 4
    for (int t = 0; t < nt; ++t) {
        const int  n  = tbase + t * 16 + l4;
        const bool vn = n < nTrain;
        const float4* yp = (const float4*)(trainX + (size_t)(vn ? n : 0) * 16);
        float4 y0 = yp[0], y1 = yp[1], y2 = yp[2], y3 = yp[3];
        float yn =
            ((y0.x*y0.x + y0.y*y0.y) + (y0.z*y0.z + y0.w*y0.w)) +
            ((y1.x*y1.x + y1.y*y1.y) + (y1.z*y1.z + y1.w*y1.w)) +
            ((y2.x*y2.x + y2.y*y2.y) + (y2.z*y2.z + y2.w*y2.w)) +
            ((y3.x*y3.x + y3.y*y3.y) + (y3.z*y3.z + y3.w*y3.w));
        yn = vn ? yn * (0.5f * LOG2E) : 1e30f;   // invalid col -> exp2 -> 0

        // B fragment: bf16-hi of this lane's 8-dim half (cndmask selects).
        short8 b;
        b[0] = (short)f2bf(h ? y2.x : y0.x);
        b[1] = (short)f2bf(h ? y2.y : y0.y);
        b[2] = (short)f2bf(h ? y2.z : y0.z);
        b[3] = (short)f2bf(h ? y2.w : y0.w);
        b[4] = (short)f2bf(h ? y3.x : y1.x);
        b[5] = (short)f2bf(h ? y3.y : y1.y);
        b[6] = (short)f2bf(h ? y3.z : y1.z);
        b[7] = (short)f2bf(h ? y3.w : y1.w);

        f32x4 c;
        c[0] = nx[0] - yn; c[1] = nx[1] - yn;
        c[2] = nx[2] - yn; c[3] = nx[3] - yn;
        c = __builtin_amdgcn_mfma_f32_16x16x32_bf16(afrag, b, c, 0, 0, 0);
        rs0 += __builtin_amdgcn_exp2f(c[0]);
        rs1 += __builtin_amdgcn_exp2f(c[1]);
        rs2 += __builtin_amdgcn_exp2f(c[2]);
        rs3 += __builtin_amdgcn_exp2f(c[3]);
    }

    // Reduce across the 16 columns (low-4 lane bits).
    #pragma unroll
    for (int off = 1; off <= 8; off <<= 1) {
        rs0 += __shfl_xor(rs0, off);
        rs1 += __shfl_xor(rs1, off);
        rs2 += __shfl_xor(rs2, off);
        rs3 += __shfl_xor(rs3, off);
    }
    if (l4 == 0) {
        red[w][g * 4 + 0] = rs0;
        red[w][g * 4 + 1] = rs1;
        red[w][g * 4 + 2] = rs2;
        red[w][g * 4 + 3] = rs3;
    }
    __syncthreads();

    if (tid < 16) {
        float s = 0.0f;
        #pragma unroll
        for (int k = 0; k < 8; ++k) s += red[k][tid];
        const int row = rowBase + tid;
        if (row < nTest) out[row] = __logf(s) - Z;
    }
}

extern "C" void kernel_launch(void* const* d_in, const int* in_sizes, int n_in,
                              void* d_out, int out_size, void* d_ws, size_t ws_size,
                              hipStream_t stream) {
    const float* testX  = (const float*)d_in[0];
    const float* trainX = (const float*)d_in[1];
    float* out = (float*)d_out;

    const int D = 16;
    const int nTest  = in_sizes[0] / D;   // 4096
    const int nTrain = in_sizes[1] / D;   // 8192

    const float Z = 0.5f * (float)D * logf(2.0f * (float)M_PI) + logf((float)nTrain);

    const int grid = (nTest + 15) / 16;   // 256 blocks, 16 rows each
    kde_fused<<<grid, 512, 0, stream>>>(testX, trainX, out, nTest, nTrain, Z);
}

// Round 6
// 24.031 us; speedup vs baseline: 4.2325x; 1.4976x over previous
//
#include <hip/hip_runtime.h>
#include <math.h>

#define LOG2E 1.4426950408889634f

typedef short short8 __attribute__((ext_vector_type(8)));
typedef float f32x4  __attribute__((ext_vector_type(4)));

__device__ inline unsigned short f2bf(float f) {   // f32 -> bf16 bits, RNE
    unsigned int u = __float_as_uint(f);
    return (unsigned short)((u + 0x7FFFu + ((u >> 16) & 1u)) >> 16);
}

// ONE dispatch. 256 blocks x 1024 threads (16 waves). Block owns 16 test
// rows; the 16 waves partition the train set (512 pts = 32 tiles each).
// Per lane per tile: load ONLY its 8-dim half (32B), half-norm + shfl
// partner-combine, round+pack to bf16, one mfma_16x16x32_bf16
// (A=[x_hi|x_lo], B=[y_hi|y_hi]), exp2-accumulate. 2-deep load prefetch.
__global__ __launch_bounds__(1024) void kde_fused(
    const float* __restrict__ testX, const float* __restrict__ trainX,
    float* __restrict__ out, int nTest, int nTrain, float Z)
{
    const int tid  = threadIdx.x;
    const int lane = tid & 63;
    const int w    = tid >> 6;            // wave 0..15
    const int NW   = 16;
    const int g    = lane >> 4;
    const int l4   = lane & 15;
    const int h    = g & 1;               // which 8-dim half this lane holds
    const int rowBase = blockIdx.x * 16;

    __shared__ float red[16][16];

    // ---- A fragment (identical in all waves): rows rowBase..rowBase+15 ----
    const int m = min(rowBase + l4, nTest - 1);
    const float4* xp = (const float4*)(testX + (size_t)m * 16);
    float4 x0 = xp[0], x1 = xp[1], x2 = xp[2], x3 = xp[3];
    float xs[16] = {x0.x,x0.y,x0.z,x0.w, x1.x,x1.y,x1.z,x1.w,
                    x2.x,x2.y,x2.z,x2.w, x3.x,x3.y,x3.z,x3.w};
    #pragma unroll
    for (int i = 0; i < 16; ++i) xs[i] *= LOG2E;
    float xn = 0.0f;
    #pragma unroll
    for (int i = 0; i < 16; ++i) xn = fmaf(xs[i], xs[i], xn);
    xn *= 0.5f / LOG2E;                   // 0.5*log2e*||x||^2 of row rowBase+l4

    short8 afrag;
    #pragma unroll
    for (int i = 0; i < 8; ++i) {
        float fx = xs[h * 8 + i];
        unsigned short hb = f2bf(fx);
        float hf = __uint_as_float((unsigned int)hb << 16);
        unsigned short lb = f2bf(fx - hf);
        afrag[i] = (short)((g < 2) ? hb : lb);   // k<16: hi, k>=16: lo
    }

    // nx[r] = -(0.5*log2e*||x||^2) for this lane's C rows (g*4+r).
    float nx[4];
    #pragma unroll
    for (int r = 0; r < 4; ++r)
        nx[r] = -__shfl(xn, (lane & 48) + g * 4 + r);

    // ---- this wave's train slice ----
    const int per   = ((nTrain + NW * 16 - 1) / (NW * 16)) * 16;
    const int tbase = w * per;
    const int nt    = per >> 4;
    const int nMax  = nTrain - 1;

    // Prefetch tile 0 (this lane's half: 2 x float4 = 32B).
    float4 ya, yb;
    {
        int nc = min(tbase + l4, nMax);
        const float4* yp = (const float4*)(trainX + (size_t)nc * 16 + h * 8);
        ya = yp[0]; yb = yp[1];
    }

    float rs0 = 0.f, rs1 = 0.f, rs2 = 0.f, rs3 = 0.f;
    #pragma unroll 2
    for (int t = 0; t < nt; ++t) {
        float4 za = ya, zb = yb;
        // Prefetch next tile (clamped; harmless overread of valid memory).
        {
            int nc2 = min(tbase + (t + 1) * 16 + l4, nMax);
            const float4* yq = (const float4*)(trainX + (size_t)nc2 * 16 + h * 8);
            ya = yq[0]; yb = yq[1];
        }
        const int n = tbase + t * 16 + l4;

        // Half-norm, combine with partner lane (lane^16 holds other half).
        float pn = ((za.x*za.x + za.y*za.y) + (za.z*za.z + za.w*za.w))
                 + ((zb.x*zb.x + zb.y*zb.y) + (zb.z*zb.z + zb.w*zb.w));
        float yn = (pn + __shfl_xor(pn, 16)) * (0.5f * LOG2E);
        yn = (n <= nMax) ? yn : 1e30f;     // invalid col -> exp2 -> 0

        // Round + pack 8 f32 -> 4 u32 of 2xbf16 (round-half-up).
        unsigned int ua0 = __float_as_uint(za.x) + 0x8000u;
        unsigned int ua1 = __float_as_uint(za.y) + 0x8000u;
        unsigned int ua2 = __float_as_uint(za.z) + 0x8000u;
        unsigned int ua3 = __float_as_uint(za.w) + 0x8000u;
        unsigned int ub0 = __float_as_uint(zb.x) + 0x8000u;
        unsigned int ub1 = __float_as_uint(zb.y) + 0x8000u;
        unsigned int ub2 = __float_as_uint(zb.z) + 0x8000u;
        unsigned int ub3 = __float_as_uint(zb.w) + 0x8000u;
        union { unsigned int u[4]; short8 s; } bb;
        bb.u[0] = (ua0 >> 16) | (ua1 & 0xFFFF0000u);
        bb.u[1] = (ua2 >> 16) | (ua3 & 0xFFFF0000u);
        bb.u[2] = (ub0 >> 16) | (ub1 & 0xFFFF0000u);
        bb.u[3] = (ub2 >> 16) | (ub3 & 0xFFFF0000u);

        f32x4 c;
        c[0] = nx[0] - yn; c[1] = nx[1] - yn;
        c[2] = nx[2] - yn; c[3] = nx[3] - yn;
        c = __builtin_amdgcn_mfma_f32_16x16x32_bf16(afrag, bb.s, c, 0, 0, 0);
        rs0 += __builtin_amdgcn_exp2f(c[0]);
        rs1 += __builtin_amdgcn_exp2f(c[1]);
        rs2 += __builtin_amdgcn_exp2f(c[2]);
        rs3 += __builtin_amdgcn_exp2f(c[3]);
    }

    // Reduce across the 16 columns (low-4 lane bits).
    #pragma unroll
    for (int off = 1; off <= 8; off <<= 1) {
        rs0 += __shfl_xor(rs0, off);
        rs1 += __shfl_xor(rs1, off);
        rs2 += __shfl_xor(rs2, off);
        rs3 += __shfl_xor(rs3, off);
    }
    if (l4 == 0) {
        red[w][g * 4 + 0] = rs0;
        red[w][g * 4 + 1] = rs1;
        red[w][g * 4 + 2] = rs2;
        red[w][g * 4 + 3] = rs3;
    }
    __syncthreads();

    if (tid < 16) {
        float s = 0.0f;
        #pragma unroll
        for (int k = 0; k < 16; ++k) s += red[k][tid];
        const int row = rowBase + tid;
        if (row < nTest) out[row] = __logf(s) - Z;
    }
}

extern "C" void kernel_launch(void* const* d_in, const int* in_sizes, int n_in,
                              void* d_out, int out_size, void* d_ws, size_t ws_size,
                              hipStream_t stream) {
    const float* testX  = (const float*)d_in[0];
    const float* trainX = (const float*)d_in[1];
    float* out = (float*)d_out;

    const int D = 16;
    const int nTest  = in_sizes[0] / D;   // 4096
    const int nTrain = in_sizes[1] / D;   // 8192

    const float Z = 0.5f * (float)D * logf(2.0f * (float)M_PI) + logf((float)nTrain);

    const int grid = (nTest + 15) / 16;   // 256 blocks, 16 rows each
    kde_fused<<<grid, 1024, 0, stream>>>(testX, trainX, out, nTest, nTrain, Z);
}

// Round 7
// 23.365 us; speedup vs baseline: 4.3532x; 1.0285x over previous
//
#include <hip/hip_runtime.h>
#include <math.h>

#define LOG2E 1.4426950408889634f

typedef short short8 __attribute__((ext_vector_type(8)));
typedef float f32x4  __attribute__((ext_vector_type(4)));

__device__ inline unsigned short f2bf(float f) {   // f32 -> bf16 bits, RNE
    unsigned int u = __float_as_uint(f);
    return (unsigned short)((u + 0x7FFFu + ((u >> 16) & 1u)) >> 16);
}

__device__ inline unsigned int cvtpk_bf16(float lo, float hi) {
    unsigned int r;
    asm("v_cvt_pk_bf16_f32 %0, %1, %2" : "=v"(r) : "v"(lo), "v"(hi));
    return r;   // low16 = bf16(lo), high16 = bf16(hi)
}

// ONE dispatch. 256 blocks x 1024 threads (16 waves). Block owns 16 test
// rows; waves partition train (512 pts = 32 tiles each). Explicit 3-stage
// software pipeline: load(t+2) || prep(t+1) || mfma+exp2(t).
__global__ __launch_bounds__(1024) void kde_fused(
    const float* __restrict__ testX, const float* __restrict__ trainX,
    float* __restrict__ out, int nTest, int nTrain, float Z)
{
    const int tid  = threadIdx.x;
    const int lane = tid & 63;
    const int w    = tid >> 6;            // wave 0..15
    const int NW   = 16;
    const int g    = lane >> 4;
    const int l4   = lane & 15;
    const int h    = g & 1;               // which 8-dim half this lane holds
    const int rowBase = blockIdx.x * 16;

    __shared__ float red[16][16];

    // ---- A fragment (identical in all waves): rows rowBase..rowBase+15 ----
    const int m = min(rowBase + l4, nTest - 1);
    const float4* xp = (const float4*)(testX + (size_t)m * 16);
    float4 x0 = xp[0], x1 = xp[1], x2 = xp[2], x3 = xp[3];
    float xs[16] = {x0.x,x0.y,x0.z,x0.w, x1.x,x1.y,x1.z,x1.w,
                    x2.x,x2.y,x2.z,x2.w, x3.x,x3.y,x3.z,x3.w};
    #pragma unroll
    for (int i = 0; i < 16; ++i) xs[i] *= LOG2E;
    float xn = 0.0f;
    #pragma unroll
    for (int i = 0; i < 16; ++i) xn = fmaf(xs[i], xs[i], xn);
    xn *= 0.5f / LOG2E;                   // 0.5*log2e*||x||^2 of row rowBase+l4

    short8 afrag;
    #pragma unroll
    for (int i = 0; i < 8; ++i) {
        float fx = xs[h * 8 + i];
        unsigned short hb = f2bf(fx);
        float hf = __uint_as_float((unsigned int)hb << 16);
        unsigned short lb = f2bf(fx - hf);
        afrag[i] = (short)((g < 2) ? hb : lb);   // k<16: hi, k>=16: lo
    }

    // nx[r] = -(0.5*log2e*||x||^2) for this lane's C rows (g*4+r).
    float nx[4];
    #pragma unroll
    for (int r = 0; r < 4; ++r)
        nx[r] = -__shfl(xn, (lane & 48) + g * 4 + r);

    // ---- this wave's train slice ----
    const int per   = ((nTrain + NW * 16 - 1) / (NW * 16)) * 16;
    const int tbase = w * per;
    const int nt    = per >> 4;
    const int nMax  = nTrain - 1;

    auto loadTile = [&](int t, float4& a, float4& b) {
        int nc = min(tbase + t * 16 + l4, nMax);
        const float4* yp = (const float4*)(trainX + (size_t)nc * 16 + h * 8);
        a = yp[0]; b = yp[1];
    };
    auto prepTile = [&](int t, const float4& za, const float4& zb,
                        short8& bs, float& yn) {
        float pn = ((za.x*za.x + za.y*za.y) + (za.z*za.z + za.w*za.w))
                 + ((zb.x*zb.x + zb.y*zb.y) + (zb.z*zb.z + zb.w*zb.w));
        float y = (pn + __shfl_xor(pn, 16)) * (0.5f * LOG2E);
        yn = (tbase + t * 16 + l4 <= nMax) ? y : 1e30f;  // invalid -> exp2 -> 0
        union { unsigned int u[4]; short8 s; } bb;
        bb.u[0] = cvtpk_bf16(za.x, za.y);
        bb.u[1] = cvtpk_bf16(za.z, za.w);
        bb.u[2] = cvtpk_bf16(zb.x, zb.y);
        bb.u[3] = cvtpk_bf16(zb.z, zb.w);
        bs = bb.s;
    };

    float rsA[4] = {0,0,0,0}, rsB[4] = {0,0,0,0};
    auto mexp = [&](const short8& bs, float yn, float* rs) {
        f32x4 c;
        c[0] = nx[0] - yn; c[1] = nx[1] - yn;
        c[2] = nx[2] - yn; c[3] = nx[3] - yn;
        c = __builtin_amdgcn_mfma_f32_16x16x32_bf16(afrag, bs, c, 0, 0, 0);
        rs[0] += __builtin_amdgcn_exp2f(c[0]);
        rs[1] += __builtin_amdgcn_exp2f(c[1]);
        rs[2] += __builtin_amdgcn_exp2f(c[2]);
        rs[3] += __builtin_amdgcn_exp2f(c[3]);
    };

    // ---- software pipeline: L(t+2) | P(t+1) | M(t), manually 2x unrolled ----
    float4 p0a, p0b, p1a, p1b;
    short8 bs0, bs1;
    float  yn0, yn1;
    loadTile(0, p0a, p0b);
    loadTile(1, p1a, p1b);
    prepTile(0, p0a, p0b, bs0, yn0);
    for (int t = 0; t < nt; t += 2) {
        loadTile(t + 2, p0a, p0b);          // p0 raw already consumed
        prepTile(t + 1, p1a, p1b, bs1, yn1);
        mexp(bs0, yn0, rsA);                // tile t
        loadTile(t + 3, p1a, p1b);
        prepTile(t + 2, p0a, p0b, bs0, yn0);
        mexp(bs1, yn1, rsB);                // tile t+1
    }

    // Merge even/odd accumulators, reduce across the 16 columns.
    float rs0 = rsA[0] + rsB[0], rs1 = rsA[1] + rsB[1];
    float rs2 = rsA[2] + rsB[2], rs3 = rsA[3] + rsB[3];
    #pragma unroll
    for (int off = 1; off <= 8; off <<= 1) {
        rs0 += __shfl_xor(rs0, off);
        rs1 += __shfl_xor(rs1, off);
        rs2 += __shfl_xor(rs2, off);
        rs3 += __shfl_xor(rs3, off);
    }
    if (l4 == 0) {
        red[w][g * 4 + 0] = rs0;
        red[w][g * 4 + 1] = rs1;
        red[w][g * 4 + 2] = rs2;
        red[w][g * 4 + 3] = rs3;
    }
    __syncthreads();

    if (tid < 16) {
        float s = 0.0f;
        #pragma unroll
        for (int k = 0; k < 16; ++k) s += red[k][tid];
        const int row = rowBase + tid;
        if (row < nTest) out[row] = __logf(s) - Z;
    }
}

extern "C" void kernel_launch(void* const* d_in, const int* in_sizes, int n_in,
                              void* d_out, int out_size, void* d_ws, size_t ws_size,
                              hipStream_t stream) {
    const float* testX  = (const float*)d_in[0];
    const float* trainX = (const float*)d_in[1];
    float* out = (float*)d_out;

    const int D = 16;
    const int nTest  = in_sizes[0] / D;   // 4096
    const int nTrain = in_sizes[1] / D;   // 8192

    const float Z = 0.5f * (float)D * logf(2.0f * (float)M_PI) + logf((float)nTrain);

    const int grid = (nTest + 15) / 16;   // 256 blocks, 16 rows each
    kde_fused<<<grid, 1024, 0, stream>>>(testX, trainX, out, nTest, nTrain, Z);
}